// Round 5
// baseline (4442.006 us; speedup 1.0000x reference)
//
#include <hip/hip_runtime.h>
#include <hip/hip_bf16.h>
#include <float.h>

#define NROWS 32768
#define EMB 1024
#define CBN 256
#define TD 32

#define OUT_CODES_OFF (33554432UL)            // 32768*1024
#define OUT_LOSS_OFF  (34603008UL)            // + 32768*32
#define TAU 1e-5f
#define INV_N (1.0f/33554432.0f)

// ---------------- Kernel A: f32 GEMM1 (skills@enc_w^T+b) fused with VQ screen --------
// grid 256 blocks x 512 thr; BM=128 rows/block, 8 n-tiles of 128 cols, BK=32.
// Near-tie tokens (f32 margin < TAU) get code written as bj+512 (in-band marker).
__launch_bounds__(512)
__global__ void k_enc_vq(const float* __restrict__ skills,
                         const float* __restrict__ enc_w,
                         const float* __restrict__ enc_b,
                         const float* __restrict__ cb_g,
                         float* __restrict__ out)
{
    __shared__ float At[32][132];
    __shared__ float Bt[32][132];
    __shared__ float stash[128][132];
    __shared__ float cb[CBN][TD];
    __shared__ float cnorm[CBN];

    const int tid = threadIdx.x;
    const int r0 = blockIdx.x * 128;

    {
        const float4* src = (const float4*)cb_g;
        float4* dst = (float4*)&cb[0][0];
        for (int i = tid; i < CBN*TD/4; i += 512) dst[i] = src[i];
    }
    __syncthreads();
    if (tid < CBN) {
        float s = 0.f;
        #pragma unroll
        for (int d = 0; d < TD; ++d) s = fmaf(cb[tid][d], cb[tid][d], s);
        cnorm[tid] = s;
    }

    const int tx = tid & 15;
    const int ty = tid >> 4;
    const int srow = tid >> 2;
    const int sq = tid & 3;

    float vq_local = 0.f;

    for (int nt = 0; nt < 8; ++nt) {
        const int n0 = nt * 128;
        float acc[4][8];
        #pragma unroll
        for (int i = 0; i < 4; ++i)
            #pragma unroll
            for (int j = 0; j < 8; ++j) acc[i][j] = 0.f;

        for (int kt = 0; kt < 32; ++kt) {
            __syncthreads();
            const int k0 = kt * 32;
            #pragma unroll
            for (int q = sq; q < 8; q += 4) {
                float4 v = *(const float4*)&skills[(size_t)(r0 + srow) * 1024 + k0 + q * 4];
                At[q*4+0][srow] = v.x; At[q*4+1][srow] = v.y;
                At[q*4+2][srow] = v.z; At[q*4+3][srow] = v.w;
                float4 w = *(const float4*)&enc_w[(size_t)(n0 + srow) * 1024 + k0 + q * 4];
                Bt[q*4+0][srow] = w.x; Bt[q*4+1][srow] = w.y;
                Bt[q*4+2][srow] = w.z; Bt[q*4+3][srow] = w.w;
            }
            __syncthreads();
            #pragma unroll 8
            for (int k = 0; k < 32; ++k) {
                float4 a  = *(const float4*)&At[k][ty * 4];
                float4 b0 = *(const float4*)&Bt[k][tx * 8];
                float4 b1 = *(const float4*)&Bt[k][tx * 8 + 4];
                float av[4] = {a.x, a.y, a.z, a.w};
                float bv[8] = {b0.x, b0.y, b0.z, b0.w, b1.x, b1.y, b1.z, b1.w};
                #pragma unroll
                for (int i = 0; i < 4; ++i)
                    #pragma unroll
                    for (int j = 0; j < 8; ++j)
                        acc[i][j] = fmaf(av[i], bv[j], acc[i][j]);
            }
        }
        __syncthreads();
        #pragma unroll
        for (int i = 0; i < 4; ++i) {
            const int col = tx * 8;
            #pragma unroll
            for (int j = 0; j < 8; ++j)
                stash[ty*4+i][col+j] = acc[i][j] + enc_b[n0 + col + j];
        }
        __syncthreads();
        // VQ screen: one token per thread
        {
            const int row = tid >> 2;
            const int s   = tid & 3;
            float f[32];
            #pragma unroll
            for (int d4 = 0; d4 < 8; ++d4) {
                float4 v = *(const float4*)&stash[row][s * 32 + d4 * 4];
                f[d4*4+0] = v.x; f[d4*4+1] = v.y; f[d4*4+2] = v.z; f[d4*4+3] = v.w;
            }
            float F = 0.f;
            #pragma unroll
            for (int d = 0; d < 32; ++d) F = fmaf(f[d], f[d], F);
            float s1 = FLT_MAX, s2 = FLT_MAX;
            int bj = 0;
            for (int j = 0; j < CBN; ++j) {
                float G = 0.f;
                const float4* cbr = (const float4*)&cb[j][0];
                #pragma unroll
                for (int d4 = 0; d4 < 8; ++d4) {
                    float4 c = cbr[d4];
                    G = fmaf(f[d4*4+0], c.x, G);
                    G = fmaf(f[d4*4+1], c.y, G);
                    G = fmaf(f[d4*4+2], c.z, G);
                    G = fmaf(f[d4*4+3], c.w, G);
                }
                float sc = fmaf(-2.f, G, cnorm[j]);
                if (sc < s1)      { s2 = s1; s1 = sc; bj = j; }
                else if (sc < s2) { s2 = sc; }
            }
            const int ltok = row * 32 + nt * 4 + s;
            float cv = (s2 - s1 < TAU) ? (float)(bj + 512) : (float)bj;
            out[OUT_CODES_OFF + (size_t)r0 * 32 + ltok] = cv;
            vq_local += F + s1;
        }
        __syncthreads();
    }
    {
        float v = vq_local;
        #pragma unroll
        for (int off = 32; off >= 1; off >>= 1) v += __shfl_xor(v, off);
        if ((tid & 63) == 0) atomicAdd(&out[OUT_LOSS_OFF], v * (1.25f * INV_N));
    }
}

// ---------------- Kernel F: faithful numpy-f32 fixup of marked tokens ---------------
// projected: OpenBLAS-replica sgemm f32 (kc=384 serial-FMA panels, ((v1+v2)+v3)+bias).
// F, cnorm: numpy scalar pairwise-32 sum of fl(x*x) (8-acc + fixed tree).
// dists = (F - 2*g) + cn, all f32 (numpy elementwise order); first-min argmin.
__global__ void k_fix(const float* __restrict__ skills,
                      const float* __restrict__ enc_w,
                      const float* __restrict__ enc_b,
                      const float* __restrict__ cb_g,
                      float* __restrict__ codes)
{
    const int tok = blockIdx.x * 256 + threadIdx.x;   // [0, 1048576)
    const int c = (int)codes[tok];
    if (c < 512) return;                               // not marked

    const int row = tok >> 5;
    const int t   = tok & 31;

    // --- replica f32 projected ---
    float p[32];
    const float* srw = &skills[(size_t)row * 1024];
    for (int d = 0; d < 32; ++d) {
        const float* wrw = &enc_w[(size_t)(t * 32 + d) * 1024];
        float v1 = 0.f, v2 = 0.f, v3 = 0.f;
        for (int q = 0; q < 384; ++q)    v1 = fmaf(srw[q], wrw[q], v1);
        for (int q = 384; q < 768; ++q)  v2 = fmaf(srw[q], wrw[q], v2);
        for (int q = 768; q < 1024; ++q) v3 = fmaf(srw[q], wrw[q], v3);
        p[d] = ((v1 + v2) + v3) + enc_b[t * 32 + d];
    }
    // --- F = np.sum(p*p) : scalar pairwise, n=32 path ---
    float F;
    {
        float s[32];
        #pragma unroll
        for (int d = 0; d < 32; ++d) s[d] = p[d] * p[d];
        float r[8];
        #pragma unroll
        for (int j = 0; j < 8; ++j) r[j] = ((s[j] + s[8+j]) + s[16+j]) + s[24+j];
        F = ((r[0] + r[1]) + (r[2] + r[3])) + ((r[4] + r[5]) + (r[6] + r[7]));
    }
    // --- dists, numpy f32 semantics ---
    float bs = FLT_MAX; int bj = 0;
    for (int j = 0; j < CBN; ++j) {
        const float* cj = &cb_g[j * 32];
        float g = 0.f;
        #pragma unroll
        for (int d = 0; d < 32; ++d) g = fmaf(p[d], cj[d], g);   // serial sgemm chain
        float cs[32];
        #pragma unroll
        for (int d = 0; d < 32; ++d) cs[d] = cj[d] * cj[d];
        float r[8];
        #pragma unroll
        for (int jj = 0; jj < 8; ++jj) r[jj] = ((cs[jj] + cs[8+jj]) + cs[16+jj]) + cs[24+jj];
        float cn = ((r[0] + r[1]) + (r[2] + r[3])) + ((r[4] + r[5]) + (r[6] + r[7]));
        float dist = (F - 2.0f * g) + cn;                        // ((F - 2G) + C) in f32
        if (dist < bs) { bs = dist; bj = j; }
    }
    codes[tok] = (float)bj;
}

// ---------------- Kernel B: f32 GEMM2 (quantized@dec_w^T+b) + recon loss -------------
__launch_bounds__(512)
__global__ void k_dec(const float* __restrict__ skills,
                      const float* __restrict__ cb_g,
                      const float* __restrict__ dec_w,
                      const float* __restrict__ dec_b,
                      const float* __restrict__ out_codes,
                      float* __restrict__ recon,
                      float* __restrict__ loss_out)
{
    __shared__ float Qt[32][132];
    __shared__ float Wt[32][132];
    const int tid = threadIdx.x;
    const int r0 = (blockIdx.x >> 3) * 128;
    const int n0 = (blockIdx.x & 7) * 128;
    const int tx = tid & 15, ty = tid >> 4;
    const int srow = tid >> 2, sq = tid & 3;

    float acc[4][8];
    #pragma unroll
    for (int i = 0; i < 4; ++i)
        #pragma unroll
        for (int j = 0; j < 8; ++j) acc[i][j] = 0.f;

    for (int t = 0; t < 32; ++t) {
        __syncthreads();
        {
            const int code = ((int)out_codes[(size_t)(r0 + srow) * 32 + t]) & 255;
            const float4* cbr = (const float4*)&cb_g[code * 32];
            float4 c0 = cbr[sq * 2], c1 = cbr[sq * 2 + 1];
            Qt[sq*8+0][srow] = c0.x; Qt[sq*8+1][srow] = c0.y;
            Qt[sq*8+2][srow] = c0.z; Qt[sq*8+3][srow] = c0.w;
            Qt[sq*8+4][srow] = c1.x; Qt[sq*8+5][srow] = c1.y;
            Qt[sq*8+6][srow] = c1.z; Qt[sq*8+7][srow] = c1.w;
            #pragma unroll
            for (int q = sq; q < 8; q += 4) {
                float4 w = *(const float4*)&dec_w[(size_t)(n0 + srow) * 1024 + t * 32 + q * 4];
                Wt[q*4+0][srow] = w.x; Wt[q*4+1][srow] = w.y;
                Wt[q*4+2][srow] = w.z; Wt[q*4+3][srow] = w.w;
            }
        }
        __syncthreads();
        #pragma unroll 8
        for (int k = 0; k < 32; ++k) {
            float4 a  = *(const float4*)&Qt[k][ty * 4];
            float4 b0 = *(const float4*)&Wt[k][tx * 8];
            float4 b1 = *(const float4*)&Wt[k][tx * 8 + 4];
            float av[4] = {a.x, a.y, a.z, a.w};
            float bv[8] = {b0.x, b0.y, b0.z, b0.w, b1.x, b1.y, b1.z, b1.w};
            #pragma unroll
            for (int i = 0; i < 4; ++i)
                #pragma unroll
                for (int j = 0; j < 8; ++j)
                    acc[i][j] = fmaf(av[i], bv[j], acc[i][j]);
        }
    }
    float lsum = 0.f;
    #pragma unroll
    for (int i = 0; i < 4; ++i) {
        const int row = r0 + ty * 4 + i;
        const int col = n0 + tx * 8;
        float rv[8];
        #pragma unroll
        for (int j = 0; j < 8; ++j) {
            rv[j] = acc[i][j] + dec_b[col + j];
            float dv = rv[j] - skills[(size_t)row * 1024 + col + j];
            lsum = fmaf(dv, dv, lsum);
        }
        *(float4*)&recon[(size_t)row * 1024 + col]     = make_float4(rv[0], rv[1], rv[2], rv[3]);
        *(float4*)&recon[(size_t)row * 1024 + col + 4] = make_float4(rv[4], rv[5], rv[6], rv[7]);
    }
    #pragma unroll
    for (int off = 32; off >= 1; off >>= 1) lsum += __shfl_xor(lsum, off);
    if ((tid & 63) == 0) atomicAdd(loss_out, lsum * INV_N);
}

extern "C" void kernel_launch(void* const* d_in, const int* in_sizes, int n_in,
                              void* d_out, int out_size, void* d_ws, size_t ws_size,
                              hipStream_t stream)
{
    const float* skills = (const float*)d_in[0];
    const float* enc_w  = (const float*)d_in[1];
    const float* enc_b  = (const float*)d_in[2];
    const float* cbg    = (const float*)d_in[3];
    const float* dec_w  = (const float*)d_in[4];
    const float* dec_b  = (const float*)d_in[5];
    float* out = (float*)d_out;

    hipMemsetAsync(out + OUT_LOSS_OFF, 0, 4, stream);
    k_enc_vq<<<dim3(256), dim3(512), 0, stream>>>(skills, enc_w, enc_b, cbg, out);
    k_fix<<<dim3(4096), dim3(256), 0, stream>>>(skills, enc_w, enc_b, cbg, out + OUT_CODES_OFF);
    k_dec<<<dim3(2048), dim3(512), 0, stream>>>(skills, cbg, dec_w, dec_b,
                                                out + OUT_CODES_OFF, out, out + OUT_LOSS_OFF);
}

// Round 6
// 2542.285 us; speedup vs baseline: 1.7472x; 1.7472x over previous
//
#include <hip/hip_runtime.h>
#include <hip/hip_bf16.h>
#include <float.h>

#define NROWS 32768
#define EMB 1024
#define CBN 256
#define TD 32

#define OUT_CODES_OFF (33554432UL)            // 32768*1024
#define OUT_LOSS_OFF  (34603008UL)            // + 32768*32
#define TAU 1e-5f
#define INV_N (1.0f/33554432.0f)

// ---------------- Kernel A: f32 GEMM1 (skills@enc_w^T+b) fused with VQ screen --------
// grid 256 blocks x 512 thr; BM=128 rows/block, 8 n-tiles of 128 cols, BK=32.
// Near-tie tokens (f32 margin < TAU) get code written as bj+512 (in-band marker).
__launch_bounds__(512)
__global__ void k_enc_vq(const float* __restrict__ skills,
                         const float* __restrict__ enc_w,
                         const float* __restrict__ enc_b,
                         const float* __restrict__ cb_g,
                         float* __restrict__ out)
{
    __shared__ float At[32][132];
    __shared__ float Bt[32][132];
    __shared__ float stash[128][132];
    __shared__ float cb[CBN][TD];
    __shared__ float cnorm[CBN];

    const int tid = threadIdx.x;
    const int r0 = blockIdx.x * 128;

    {
        const float4* src = (const float4*)cb_g;
        float4* dst = (float4*)&cb[0][0];
        for (int i = tid; i < CBN*TD/4; i += 512) dst[i] = src[i];
    }
    __syncthreads();
    if (tid < CBN) {
        float s = 0.f;
        #pragma unroll
        for (int d = 0; d < TD; ++d) s = fmaf(cb[tid][d], cb[tid][d], s);
        cnorm[tid] = s;
    }

    const int tx = tid & 15;
    const int ty = tid >> 4;
    const int srow = tid >> 2;
    const int sq = tid & 3;

    float vq_local = 0.f;

    for (int nt = 0; nt < 8; ++nt) {
        const int n0 = nt * 128;
        float acc[4][8];
        #pragma unroll
        for (int i = 0; i < 4; ++i)
            #pragma unroll
            for (int j = 0; j < 8; ++j) acc[i][j] = 0.f;

        for (int kt = 0; kt < 32; ++kt) {
            __syncthreads();
            const int k0 = kt * 32;
            #pragma unroll
            for (int q = sq; q < 8; q += 4) {
                float4 v = *(const float4*)&skills[(size_t)(r0 + srow) * 1024 + k0 + q * 4];
                At[q*4+0][srow] = v.x; At[q*4+1][srow] = v.y;
                At[q*4+2][srow] = v.z; At[q*4+3][srow] = v.w;
                float4 w = *(const float4*)&enc_w[(size_t)(n0 + srow) * 1024 + k0 + q * 4];
                Bt[q*4+0][srow] = w.x; Bt[q*4+1][srow] = w.y;
                Bt[q*4+2][srow] = w.z; Bt[q*4+3][srow] = w.w;
            }
            __syncthreads();
            #pragma unroll 8
            for (int k = 0; k < 32; ++k) {
                float4 a  = *(const float4*)&At[k][ty * 4];
                float4 b0 = *(const float4*)&Bt[k][tx * 8];
                float4 b1 = *(const float4*)&Bt[k][tx * 8 + 4];
                float av[4] = {a.x, a.y, a.z, a.w};
                float bv[8] = {b0.x, b0.y, b0.z, b0.w, b1.x, b1.y, b1.z, b1.w};
                #pragma unroll
                for (int i = 0; i < 4; ++i)
                    #pragma unroll
                    for (int j = 0; j < 8; ++j)
                        acc[i][j] = fmaf(av[i], bv[j], acc[i][j]);
            }
        }
        __syncthreads();
        #pragma unroll
        for (int i = 0; i < 4; ++i) {
            const int col = tx * 8;
            #pragma unroll
            for (int j = 0; j < 8; ++j)
                stash[ty*4+i][col+j] = acc[i][j] + enc_b[n0 + col + j];
        }
        __syncthreads();
        // VQ screen: one token per thread
        {
            const int row = tid >> 2;
            const int s   = tid & 3;
            float f[32];
            #pragma unroll
            for (int d4 = 0; d4 < 8; ++d4) {
                float4 v = *(const float4*)&stash[row][s * 32 + d4 * 4];
                f[d4*4+0] = v.x; f[d4*4+1] = v.y; f[d4*4+2] = v.z; f[d4*4+3] = v.w;
            }
            float F = 0.f;
            #pragma unroll
            for (int d = 0; d < 32; ++d) F = fmaf(f[d], f[d], F);
            float s1 = FLT_MAX, s2 = FLT_MAX;
            int bj = 0;
            for (int j = 0; j < CBN; ++j) {
                float G = 0.f;
                const float4* cbr = (const float4*)&cb[j][0];
                #pragma unroll
                for (int d4 = 0; d4 < 8; ++d4) {
                    float4 c = cbr[d4];
                    G = fmaf(f[d4*4+0], c.x, G);
                    G = fmaf(f[d4*4+1], c.y, G);
                    G = fmaf(f[d4*4+2], c.z, G);
                    G = fmaf(f[d4*4+3], c.w, G);
                }
                float sc = fmaf(-2.f, G, cnorm[j]);
                if (sc < s1)      { s2 = s1; s1 = sc; bj = j; }
                else if (sc < s2) { s2 = sc; }
            }
            const int ltok = row * 32 + nt * 4 + s;
            float cv = (s2 - s1 < TAU) ? (float)(bj + 512) : (float)bj;
            out[OUT_CODES_OFF + (size_t)r0 * 32 + ltok] = cv;
            vq_local += F + s1;
        }
        __syncthreads();
    }
    {
        float v = vq_local;
        #pragma unroll
        for (int off = 32; off >= 1; off >>= 1) v += __shfl_xor(v, off);
        if ((tid & 63) == 0) atomicAdd(&out[OUT_LOSS_OFF], v * (1.25f * INV_N));
    }
}

// ---------------- Kernel F: wave-cooperative faithful numpy-f32 fixup ---------------
// Bit-identical arithmetic to round-5 k_fix; parallelized: block screens 256 tokens
// into an LDS worklist, one wave per flagged token (lane d computes p[d] with the
// exact kc=384 serial chains; 256 codewords split 4-per-lane, ascending, strict <;
// cross-lane lexicographic (dist,j) reduce == serial first-min).
__launch_bounds__(256)
__global__ void k_fix(const float* __restrict__ skills,
                      const float* __restrict__ enc_w,
                      const float* __restrict__ enc_b,
                      const float* __restrict__ cb_g,
                      float* __restrict__ codes)
{
    __shared__ unsigned int cnt;
    __shared__ unsigned short list[256];

    const int tid = threadIdx.x;
    const int base = blockIdx.x * 256;

    if (tid == 0) cnt = 0;
    __syncthreads();
    {
        const int c = (int)codes[base + tid];
        if (c >= 512) {
            unsigned int ix = atomicAdd(&cnt, 1u);
            list[ix] = (unsigned short)tid;
        }
    }
    __syncthreads();
    const unsigned int n = cnt;
    if (n == 0) return;

    const int wv = tid >> 6, lane = tid & 63;
    const int d = lane & 31;

    for (unsigned int i = wv; i < n; i += 4) {
        const int tok = base + (int)list[i];
        const int row = tok >> 5;
        const int t   = tok & 31;

        // --- replica f32 projected[d] on lane d (exact chain order) ---
        const float4* s4 = (const float4*)&skills[(size_t)row * 1024];
        const float4* w4 = (const float4*)&enc_w[(size_t)(t * 32 + d) * 1024];
        float v1 = 0.f, v2 = 0.f, v3 = 0.f;
        for (int q = 0; q < 96; ++q) {
            float4 a = s4[q], b = w4[q];
            v1 = fmaf(a.x, b.x, v1); v1 = fmaf(a.y, b.y, v1);
            v1 = fmaf(a.z, b.z, v1); v1 = fmaf(a.w, b.w, v1);
        }
        for (int q = 96; q < 192; ++q) {
            float4 a = s4[q], b = w4[q];
            v2 = fmaf(a.x, b.x, v2); v2 = fmaf(a.y, b.y, v2);
            v2 = fmaf(a.z, b.z, v2); v2 = fmaf(a.w, b.w, v2);
        }
        for (int q = 192; q < 256; ++q) {
            float4 a = s4[q], b = w4[q];
            v3 = fmaf(a.x, b.x, v3); v3 = fmaf(a.y, b.y, v3);
            v3 = fmaf(a.z, b.z, v3); v3 = fmaf(a.w, b.w, v3);
        }
        const float pd = ((v1 + v2) + v3) + enc_b[t * 32 + d];

        // broadcast p[0..31] to all lanes
        float pv[32];
        #pragma unroll
        for (int dd = 0; dd < 32; ++dd) pv[dd] = __shfl(pd, dd);

        // --- F = np.sum(p*p): scalar pairwise, n=32 path (identical tree) ---
        float F;
        {
            float s[32];
            #pragma unroll
            for (int dd = 0; dd < 32; ++dd) s[dd] = pv[dd] * pv[dd];
            float r[8];
            #pragma unroll
            for (int j = 0; j < 8; ++j) r[j] = ((s[j] + s[8+j]) + s[16+j]) + s[24+j];
            F = ((r[0] + r[1]) + (r[2] + r[3])) + ((r[4] + r[5]) + (r[6] + r[7]));
        }

        // --- 4 codewords per lane, ascending j, strict < (first-min) ---
        float bs = FLT_MAX; int bj = 0;
        for (int m = 0; m < 4; ++m) {
            const int j = m * 64 + lane;
            const float* cj = &cb_g[j * 32];
            float g = 0.f;
            #pragma unroll
            for (int dd = 0; dd < 32; ++dd) g = fmaf(pv[dd], cj[dd], g);
            float cs[32];
            #pragma unroll
            for (int dd = 0; dd < 32; ++dd) cs[dd] = cj[dd] * cj[dd];
            float r[8];
            #pragma unroll
            for (int jj = 0; jj < 8; ++jj) r[jj] = ((cs[jj] + cs[8+jj]) + cs[16+jj]) + cs[24+jj];
            float cn = ((r[0] + r[1]) + (r[2] + r[3])) + ((r[4] + r[5]) + (r[6] + r[7]));
            float dist = (F - 2.0f * g) + cn;
            if (dist < bs) { bs = dist; bj = j; }
        }
        // cross-lane lexicographic (dist, j) reduce
        #pragma unroll
        for (int off = 32; off >= 1; off >>= 1) {
            float os = __shfl_xor(bs, off);
            int   oj = __shfl_xor(bj, off);
            if (os < bs || (os == bs && oj < bj)) { bs = os; bj = oj; }
        }
        if (lane == 0) codes[tok] = (float)bj;
    }
}

// ---------------- Kernel B: f32 GEMM2 (quantized@dec_w^T+b) + recon loss -------------
__launch_bounds__(512)
__global__ void k_dec(const float* __restrict__ skills,
                      const float* __restrict__ cb_g,
                      const float* __restrict__ dec_w,
                      const float* __restrict__ dec_b,
                      const float* __restrict__ out_codes,
                      float* __restrict__ recon,
                      float* __restrict__ loss_out)
{
    __shared__ float Qt[32][132];
    __shared__ float Wt[32][132];
    const int tid = threadIdx.x;
    const int r0 = (blockIdx.x >> 3) * 128;
    const int n0 = (blockIdx.x & 7) * 128;
    const int tx = tid & 15, ty = tid >> 4;
    const int srow = tid >> 2, sq = tid & 3;

    float acc[4][8];
    #pragma unroll
    for (int i = 0; i < 4; ++i)
        #pragma unroll
        for (int j = 0; j < 8; ++j) acc[i][j] = 0.f;

    for (int t = 0; t < 32; ++t) {
        __syncthreads();
        {
            const int code = ((int)out_codes[(size_t)(r0 + srow) * 32 + t]) & 255;
            const float4* cbr = (const float4*)&cb_g[code * 32];
            float4 c0 = cbr[sq * 2], c1 = cbr[sq * 2 + 1];
            Qt[sq*8+0][srow] = c0.x; Qt[sq*8+1][srow] = c0.y;
            Qt[sq*8+2][srow] = c0.z; Qt[sq*8+3][srow] = c0.w;
            Qt[sq*8+4][srow] = c1.x; Qt[sq*8+5][srow] = c1.y;
            Qt[sq*8+6][srow] = c1.z; Qt[sq*8+7][srow] = c1.w;
            #pragma unroll
            for (int q = sq; q < 8; q += 4) {
                float4 w = *(const float4*)&dec_w[(size_t)(n0 + srow) * 1024 + t * 32 + q * 4];
                Wt[q*4+0][srow] = w.x; Wt[q*4+1][srow] = w.y;
                Wt[q*4+2][srow] = w.z; Wt[q*4+3][srow] = w.w;
            }
        }
        __syncthreads();
        #pragma unroll 8
        for (int k = 0; k < 32; ++k) {
            float4 a  = *(const float4*)&Qt[k][ty * 4];
            float4 b0 = *(const float4*)&Wt[k][tx * 8];
            float4 b1 = *(const float4*)&Wt[k][tx * 8 + 4];
            float av[4] = {a.x, a.y, a.z, a.w};
            float bv[8] = {b0.x, b0.y, b0.z, b0.w, b1.x, b1.y, b1.z, b1.w};
            #pragma unroll
            for (int i = 0; i < 4; ++i)
                #pragma unroll
                for (int j = 0; j < 8; ++j)
                    acc[i][j] = fmaf(av[i], bv[j], acc[i][j]);
        }
    }
    float lsum = 0.f;
    #pragma unroll
    for (int i = 0; i < 4; ++i) {
        const int row = r0 + ty * 4 + i;
        const int col = n0 + tx * 8;
        float rv[8];
        #pragma unroll
        for (int j = 0; j < 8; ++j) {
            rv[j] = acc[i][j] + dec_b[col + j];
            float dv = rv[j] - skills[(size_t)row * 1024 + col + j];
            lsum = fmaf(dv, dv, lsum);
        }
        *(float4*)&recon[(size_t)row * 1024 + col]     = make_float4(rv[0], rv[1], rv[2], rv[3]);
        *(float4*)&recon[(size_t)row * 1024 + col + 4] = make_float4(rv[4], rv[5], rv[6], rv[7]);
    }
    #pragma unroll
    for (int off = 32; off >= 1; off >>= 1) lsum += __shfl_xor(lsum, off);
    if ((tid & 63) == 0) atomicAdd(loss_out, lsum * INV_N);
}

extern "C" void kernel_launch(void* const* d_in, const int* in_sizes, int n_in,
                              void* d_out, int out_size, void* d_ws, size_t ws_size,
                              hipStream_t stream)
{
    const float* skills = (const float*)d_in[0];
    const float* enc_w  = (const float*)d_in[1];
    const float* enc_b  = (const float*)d_in[2];
    const float* cbg    = (const float*)d_in[3];
    const float* dec_w  = (const float*)d_in[4];
    const float* dec_b  = (const float*)d_in[5];
    float* out = (float*)d_out;

    hipMemsetAsync(out + OUT_LOSS_OFF, 0, 4, stream);
    k_enc_vq<<<dim3(256), dim3(512), 0, stream>>>(skills, enc_w, enc_b, cbg, out);
    k_fix<<<dim3(4096), dim3(256), 0, stream>>>(skills, enc_w, enc_b, cbg, out + OUT_CODES_OFF);
    k_dec<<<dim3(2048), dim3(512), 0, stream>>>(skills, cbg, dec_w, dec_b,
                                                out + OUT_CODES_OFF, out, out + OUT_LOSS_OFF);
}

// Round 7
// 1069.127 us; speedup vs baseline: 4.1548x; 2.3779x over previous
//
#include <hip/hip_runtime.h>
#include <hip/hip_bf16.h>
#include <float.h>

#define NROWS 32768
#define EMB 1024
#define CBN 256
#define TD 32

#define OUT_CODES_OFF (33554432UL)            // 32768*1024
#define OUT_LOSS_OFF  (34603008UL)            // + 32768*32
#define TAU 1e-5f
#define INV_N (1.0f/33554432.0f)

typedef __attribute__((ext_vector_type(8))) short s16x8;
typedef __attribute__((ext_vector_type(4))) float f32x4;

__device__ __forceinline__ unsigned short bf16r(float x) {
    unsigned int u = __float_as_uint(x);
    unsigned int r = (u + 0x7FFFu + ((u >> 16) & 1u)) >> 16;
    return (unsigned short)r;
}
__device__ __forceinline__ float bf16f(unsigned short h) {
    return __uint_as_float(((unsigned int)h) << 16);
}

// ============ Kernel A: bf16-split MFMA GEMM1 + MFMA VQ screen =====================
// grid 256 x 512thr (8 waves, 4Mx2N). BM=128 rows, nt: 8 tiles of BN=128, BK=32.
// P = skills@enc_w^T via 3-pass bf16 split (AhBh+AhBl+AlBh); scores = f@cb^T same.
// Near-tie tokens (margin < TAU) marked +512 for the bit-faithful fixup.
__launch_bounds__(512, 1)
__global__ void k_enc(const float* __restrict__ skills,
                      const float* __restrict__ enc_w,
                      const float* __restrict__ enc_b,
                      const float* __restrict__ cb_g,
                      float* __restrict__ out)
{
    __shared__ unsigned short Ah[128][40], Al[128][40];   // skills tile hi/lo
    __shared__ unsigned short Bh[128][40], Bl[128][40];   // enc_w tile hi/lo
    __shared__ unsigned short Ch[256][40], Cl[256][40];   // codebook split
    __shared__ float cnb[256];
    __shared__ unsigned short Sh[512][32], Sl[512][32];   // f stash (bf16 split)
    __shared__ float Fv[512];                             // per-token |f|^2

    const int tid = threadIdx.x;
    const int r0 = blockIdx.x * 128;
    const int wid = tid >> 6, lane = tid & 63;
    const int wm = wid >> 1, wn = wid & 1;
    const int mbase = wm * 32, nbase = wn * 64;
    const int lhi = lane >> 4, llo = lane & 15;
    const int srow = tid >> 2, sq = tid & 3;

    // ---- stage codebook split + cnorm ----
    if (tid < 256) {
        const float4* cr = (const float4*)&cb_g[tid * 32];
        float c[32];
        #pragma unroll
        for (int i = 0; i < 8; ++i) {
            float4 v = cr[i];
            c[i*4+0] = v.x; c[i*4+1] = v.y; c[i*4+2] = v.z; c[i*4+3] = v.w;
        }
        float s = 0.f;
        #pragma unroll
        for (int d = 0; d < 32; ++d) {
            unsigned short hh = bf16r(c[d]);
            Ch[tid][d] = hh;
            Cl[tid][d] = bf16r(c[d] - bf16f(hh));
            s = fmaf(c[d], c[d], s);
        }
        cnb[tid] = s;
    }
    __syncthreads();

    float vq_local = 0.f;

    for (int nt = 0; nt < 8; ++nt) {
        const int n0 = nt * 128;
        f32x4 acc[2][4];
        #pragma unroll
        for (int mf = 0; mf < 2; ++mf)
            #pragma unroll
            for (int nf = 0; nf < 4; ++nf) acc[mf][nf] = (f32x4)0.f;

        for (int kt = 0; kt < 32; ++kt) {
            __syncthreads();
            // stage A (skills) and B (enc_w) as bf16 hi/lo, 8 elems/thread each
            {
                const float* ap = &skills[(size_t)(r0 + srow) * 1024 + kt * 32 + sq * 8];
                float4 v0 = *(const float4*)ap, v1 = *(const float4*)(ap + 4);
                float xs[8] = {v0.x, v0.y, v0.z, v0.w, v1.x, v1.y, v1.z, v1.w};
                s16x8 h, l;
                #pragma unroll
                for (int e = 0; e < 8; ++e) {
                    unsigned short hh = bf16r(xs[e]);
                    h[e] = (short)hh;
                    l[e] = (short)bf16r(xs[e] - bf16f(hh));
                }
                *(s16x8*)&Ah[srow][sq * 8] = h;
                *(s16x8*)&Al[srow][sq * 8] = l;

                const float* bp = &enc_w[(size_t)(n0 + srow) * 1024 + kt * 32 + sq * 8];
                float4 w0 = *(const float4*)bp, w1 = *(const float4*)(bp + 4);
                float ys[8] = {w0.x, w0.y, w0.z, w0.w, w1.x, w1.y, w1.z, w1.w};
                #pragma unroll
                for (int e = 0; e < 8; ++e) {
                    unsigned short hh = bf16r(ys[e]);
                    h[e] = (short)hh;
                    l[e] = (short)bf16r(ys[e] - bf16f(hh));
                }
                *(s16x8*)&Bh[srow][sq * 8] = h;
                *(s16x8*)&Bl[srow][sq * 8] = l;
            }
            __syncthreads();
            s16x8 ah[2], al[2], bh[4], bl[4];
            #pragma unroll
            for (int mf = 0; mf < 2; ++mf) {
                const int row = mbase + mf * 16 + llo;
                ah[mf] = *(s16x8*)&Ah[row][lhi * 8];
                al[mf] = *(s16x8*)&Al[row][lhi * 8];
            }
            #pragma unroll
            for (int nf = 0; nf < 4; ++nf) {
                const int row = nbase + nf * 16 + llo;
                bh[nf] = *(s16x8*)&Bh[row][lhi * 8];
                bl[nf] = *(s16x8*)&Bl[row][lhi * 8];
            }
            #pragma unroll
            for (int mf = 0; mf < 2; ++mf)
                #pragma unroll
                for (int nf = 0; nf < 4; ++nf) {
                    acc[mf][nf] = __builtin_amdgcn_mfma_f32_16x16x32_bf16(ah[mf], bh[nf], acc[mf][nf], 0, 0, 0);
                    acc[mf][nf] = __builtin_amdgcn_mfma_f32_16x16x32_bf16(ah[mf], bl[nf], acc[mf][nf], 0, 0, 0);
                    acc[mf][nf] = __builtin_amdgcn_mfma_f32_16x16x32_bf16(al[mf], bh[nf], acc[mf][nf], 0, 0, 0);
                }
        }
        __syncthreads();

        // ---- bias + stash (bf16 split) + F partials ----
        float fp[2][4][2];
        #pragma unroll
        for (int mf = 0; mf < 2; ++mf)
            #pragma unroll
            for (int r = 0; r < 4; ++r) { fp[mf][r][0] = 0.f; fp[mf][r][1] = 0.f; }

        #pragma unroll
        for (int mf = 0; mf < 2; ++mf)
            #pragma unroll
            for (int nf = 0; nf < 4; ++nf) {
                const int n_local = nbase + nf * 16 + llo;
                const float bias = enc_b[n0 + n_local];
                const int tl = wn * 2 + (nf >> 1);
                const int d = ((nf & 1) << 4) + llo;
                #pragma unroll
                for (int r = 0; r < 4; ++r) {
                    const int m_local = mbase + mf * 16 + lhi * 4 + r;
                    float val = acc[mf][nf][r] + bias;
                    unsigned short hh = bf16r(val);
                    Sh[m_local * 4 + tl][d] = hh;
                    Sl[m_local * 4 + tl][d] = bf16r(val - bf16f(hh));
                    fp[mf][r][nf >> 1] = fmaf(val, val, fp[mf][r][nf >> 1]);
                }
            }
        #pragma unroll
        for (int mf = 0; mf < 2; ++mf)
            #pragma unroll
            for (int r = 0; r < 4; ++r)
                #pragma unroll
                for (int tt = 0; tt < 2; ++tt) {
                    float f = fp[mf][r][tt];
                    f += __shfl_xor(f, 1); f += __shfl_xor(f, 2);
                    f += __shfl_xor(f, 4); f += __shfl_xor(f, 8);
                    if (llo == 0)
                        Fv[(mbase + mf * 16 + lhi * 4 + r) * 4 + wn * 2 + tt] = f;
                }
        __syncthreads();

        // ---- MFMA score screen: 4 token-groups of 16 per wave ----
        #pragma unroll
        for (int gi = 0; gi < 4; ++gi) {
            const int g = wid * 4 + gi;
            const int tokrow = g * 16 + llo;
            s16x8 fh = *(s16x8*)&Sh[tokrow][lhi * 8];
            s16x8 fl = *(s16x8*)&Sl[tokrow][lhi * 8];
            float s1[4], s2[4]; int bj[4];
            #pragma unroll
            for (int r = 0; r < 4; ++r) { s1[r] = FLT_MAX; s2[r] = FLT_MAX; bj[r] = 0; }
            for (int jb = 0; jb < 16; ++jb) {
                const int j = jb * 16 + llo;
                s16x8 ch = *(s16x8*)&Ch[j][lhi * 8];
                s16x8 cl = *(s16x8*)&Cl[j][lhi * 8];
                f32x4 sc = (f32x4)0.f;
                sc = __builtin_amdgcn_mfma_f32_16x16x32_bf16(fh, ch, sc, 0, 0, 0);
                sc = __builtin_amdgcn_mfma_f32_16x16x32_bf16(fh, cl, sc, 0, 0, 0);
                sc = __builtin_amdgcn_mfma_f32_16x16x32_bf16(fl, ch, sc, 0, 0, 0);
                const float cnv = cnb[j];
                #pragma unroll
                for (int r = 0; r < 4; ++r) {
                    float s = fmaf(-2.f, sc[r], cnv);
                    if (s < s1[r])      { s2[r] = s1[r]; s1[r] = s; bj[r] = j; }
                    else if (s < s2[r]) { s2[r] = s; }
                }
            }
            // merge across the 16 lanes of each token row (offsets 1,2,4,8)
            #pragma unroll
            for (int r = 0; r < 4; ++r) {
                float a1 = s1[r], a2 = s2[r]; int aj = bj[r];
                #pragma unroll
                for (int off = 1; off <= 8; off <<= 1) {
                    float o1 = __shfl_xor(a1, off);
                    float o2 = __shfl_xor(a2, off);
                    int   oj = __shfl_xor(aj, off);
                    if (o1 < a1) { a2 = fminf(a1, o2); a1 = o1; aj = oj; }
                    else         { a2 = fminf(o1, a2); }
                }
                if (llo == 0) {
                    const int tok_local = g * 16 + lhi * 4 + r;
                    const float F = Fv[tok_local];
                    float cv = (a2 - a1 < TAU) ? (float)(aj + 512) : (float)aj;
                    const size_t tok = (size_t)(r0 + (tok_local >> 2)) * 32 + nt * 4 + (tok_local & 3);
                    out[OUT_CODES_OFF + tok] = cv;
                    vq_local += F + a1;
                }
            }
        }
        __syncthreads();
    }
    // vq loss partial (pre-scaled)
    {
        float v = vq_local;
        #pragma unroll
        for (int off = 32; off >= 1; off >>= 1) v += __shfl_xor(v, off);
        if (lane == 0) atomicAdd(&out[OUT_LOSS_OFF], v * (1.25f * INV_N));
    }
}

// ============ Kernel F: wave-cooperative faithful numpy-f32 fixup (unchanged) =======
__launch_bounds__(256)
__global__ void k_fix(const float* __restrict__ skills,
                      const float* __restrict__ enc_w,
                      const float* __restrict__ enc_b,
                      const float* __restrict__ cb_g,
                      float* __restrict__ codes)
{
    __shared__ unsigned int cnt;
    __shared__ unsigned short list[256];

    const int tid = threadIdx.x;
    const int base = blockIdx.x * 256;

    if (tid == 0) cnt = 0;
    __syncthreads();
    {
        const int c = (int)codes[base + tid];
        if (c >= 512) {
            unsigned int ix = atomicAdd(&cnt, 1u);
            list[ix] = (unsigned short)tid;
        }
    }
    __syncthreads();
    const unsigned int n = cnt;
    if (n == 0) return;

    const int wv = tid >> 6, lane = tid & 63;
    const int d = lane & 31;

    for (unsigned int i = wv; i < n; i += 4) {
        const int tok = base + (int)list[i];
        const int row = tok >> 5;
        const int t   = tok & 31;

        const float4* s4 = (const float4*)&skills[(size_t)row * 1024];
        const float4* w4 = (const float4*)&enc_w[(size_t)(t * 32 + d) * 1024];
        float v1 = 0.f, v2 = 0.f, v3 = 0.f;
        for (int q = 0; q < 96; ++q) {
            float4 a = s4[q], b = w4[q];
            v1 = fmaf(a.x, b.x, v1); v1 = fmaf(a.y, b.y, v1);
            v1 = fmaf(a.z, b.z, v1); v1 = fmaf(a.w, b.w, v1);
        }
        for (int q = 96; q < 192; ++q) {
            float4 a = s4[q], b = w4[q];
            v2 = fmaf(a.x, b.x, v2); v2 = fmaf(a.y, b.y, v2);
            v2 = fmaf(a.z, b.z, v2); v2 = fmaf(a.w, b.w, v2);
        }
        for (int q = 192; q < 256; ++q) {
            float4 a = s4[q], b = w4[q];
            v3 = fmaf(a.x, b.x, v3); v3 = fmaf(a.y, b.y, v3);
            v3 = fmaf(a.z, b.z, v3); v3 = fmaf(a.w, b.w, v3);
        }
        const float pd = ((v1 + v2) + v3) + enc_b[t * 32 + d];

        float pv[32];
        #pragma unroll
        for (int dd = 0; dd < 32; ++dd) pv[dd] = __shfl(pd, dd);

        float F;
        {
            float s[32];
            #pragma unroll
            for (int dd = 0; dd < 32; ++dd) s[dd] = pv[dd] * pv[dd];
            float r[8];
            #pragma unroll
            for (int j = 0; j < 8; ++j) r[j] = ((s[j] + s[8+j]) + s[16+j]) + s[24+j];
            F = ((r[0] + r[1]) + (r[2] + r[3])) + ((r[4] + r[5]) + (r[6] + r[7]));
        }

        float bs = FLT_MAX; int bj = 0;
        for (int m = 0; m < 4; ++m) {
            const int j = m * 64 + lane;
            const float* cj = &cb_g[j * 32];
            float g = 0.f;
            #pragma unroll
            for (int dd = 0; dd < 32; ++dd) g = fmaf(pv[dd], cj[dd], g);
            float cs[32];
            #pragma unroll
            for (int dd = 0; dd < 32; ++dd) cs[dd] = cj[dd] * cj[dd];
            float r[8];
            #pragma unroll
            for (int jj = 0; jj < 8; ++jj) r[jj] = ((cs[jj] + cs[8+jj]) + cs[16+jj]) + cs[24+jj];
            float cn = ((r[0] + r[1]) + (r[2] + r[3])) + ((r[4] + r[5]) + (r[6] + r[7]));
            float dist = (F - 2.0f * g) + cn;
            if (dist < bs) { bs = dist; bj = j; }
        }
        #pragma unroll
        for (int off = 32; off >= 1; off >>= 1) {
            float os = __shfl_xor(bs, off);
            int   oj = __shfl_xor(bj, off);
            if (os < bs || (os == bs && oj < bj)) { bs = os; bj = oj; }
        }
        if (lane == 0) codes[tok] = (float)bj;
    }
}

// ============ Kernel B: bf16 MFMA GEMM2 (quantized@dec_w^T + b) + recon loss ========
// grid 2048 (256 rb x 8 nb) x 512thr (8 waves, 4Mx2N); BM=128, BN=128, BK=32 (=1 tok)
__launch_bounds__(512)
__global__ void k_dec(const float* __restrict__ skills,
                      const float* __restrict__ cb_g,
                      const float* __restrict__ dec_w,
                      const float* __restrict__ dec_b,
                      const float* __restrict__ codes,
                      float* __restrict__ recon,
                      float* __restrict__ loss_out)
{
    __shared__ unsigned short Qt[128][40], Wt[128][40];

    const int tid = threadIdx.x;
    const int r0 = (blockIdx.x >> 3) * 128;
    const int n0 = (blockIdx.x & 7) * 128;
    const int wid = tid >> 6, lane = tid & 63;
    const int wm = wid >> 1, wn = wid & 1;
    const int mbase = wm * 32, nbase = wn * 64;
    const int lhi = lane >> 4, llo = lane & 15;
    const int srow = tid >> 2, sq = tid & 3;

    f32x4 acc[2][4];
    #pragma unroll
    for (int mf = 0; mf < 2; ++mf)
        #pragma unroll
        for (int nf = 0; nf < 4; ++nf) acc[mf][nf] = (f32x4)0.f;

    for (int t = 0; t < 32; ++t) {
        __syncthreads();
        {
            const int code = ((int)codes[(size_t)(r0 + srow) * 32 + t]) & 255;
            const float* cp = &cb_g[code * 32 + sq * 8];
            float4 c0 = *(const float4*)cp, c1 = *(const float4*)(cp + 4);
            float xs[8] = {c0.x, c0.y, c0.z, c0.w, c1.x, c1.y, c1.z, c1.w};
            s16x8 h;
            #pragma unroll
            for (int e = 0; e < 8; ++e) h[e] = (short)bf16r(xs[e]);
            *(s16x8*)&Qt[srow][sq * 8] = h;

            const float* wp = &dec_w[(size_t)(n0 + srow) * 1024 + t * 32 + sq * 8];
            float4 w0 = *(const float4*)wp, w1 = *(const float4*)(wp + 4);
            float ys[8] = {w0.x, w0.y, w0.z, w0.w, w1.x, w1.y, w1.z, w1.w};
            #pragma unroll
            for (int e = 0; e < 8; ++e) h[e] = (short)bf16r(ys[e]);
            *(s16x8*)&Wt[srow][sq * 8] = h;
        }
        __syncthreads();
        s16x8 aq[2], bw[4];
        #pragma unroll
        for (int mf = 0; mf < 2; ++mf)
            aq[mf] = *(s16x8*)&Qt[mbase + mf * 16 + llo][lhi * 8];
        #pragma unroll
        for (int nf = 0; nf < 4; ++nf)
            bw[nf] = *(s16x8*)&Wt[nbase + nf * 16 + llo][lhi * 8];
        #pragma unroll
        for (int mf = 0; mf < 2; ++mf)
            #pragma unroll
            for (int nf = 0; nf < 4; ++nf)
                acc[mf][nf] = __builtin_amdgcn_mfma_f32_16x16x32_bf16(aq[mf], bw[nf], acc[mf][nf], 0, 0, 0);
    }

    float lsum = 0.f;
    #pragma unroll
    for (int mf = 0; mf < 2; ++mf)
        #pragma unroll
        for (int nf = 0; nf < 4; ++nf) {
            const int col = n0 + nbase + nf * 16 + llo;
            const float bias = dec_b[col];
            #pragma unroll
            for (int r = 0; r < 4; ++r) {
                const int row = r0 + mbase + mf * 16 + lhi * 4 + r;
                float rv = acc[mf][nf][r] + bias;
                float dv = rv - skills[(size_t)row * 1024 + col];
                lsum = fmaf(dv, dv, lsum);
                recon[(size_t)row * 1024 + col] = rv;
            }
        }
    #pragma unroll
    for (int off = 32; off >= 1; off >>= 1) lsum += __shfl_xor(lsum, off);
    if (lane == 0) atomicAdd(loss_out, lsum * INV_N);
}

extern "C" void kernel_launch(void* const* d_in, const int* in_sizes, int n_in,
                              void* d_out, int out_size, void* d_ws, size_t ws_size,
                              hipStream_t stream)
{
    const float* skills = (const float*)d_in[0];
    const float* enc_w  = (const float*)d_in[1];
    const float* enc_b  = (const float*)d_in[2];
    const float* cbg    = (const float*)d_in[3];
    const float* dec_w  = (const float*)d_in[4];
    const float* dec_b  = (const float*)d_in[5];
    float* out = (float*)d_out;

    hipMemsetAsync(out + OUT_LOSS_OFF, 0, 4, stream);
    k_enc<<<dim3(256), dim3(512), 0, stream>>>(skills, enc_w, enc_b, cbg, out);
    k_fix<<<dim3(4096), dim3(256), 0, stream>>>(skills, enc_w, enc_b, cbg, out + OUT_CODES_OFF);
    k_dec<<<dim3(2048), dim3(512), 0, stream>>>(skills, cbg, dec_w, dec_b,
                                                out + OUT_CODES_OFF, out, out + OUT_LOSS_OFF);
}

// Round 8
// 925.341 us; speedup vs baseline: 4.8004x; 1.1554x over previous
//
#include <hip/hip_runtime.h>
#include <hip/hip_bf16.h>
#include <float.h>

#define NROWS 32768
#define EMB 1024
#define CBN 256
#define TD 32

#define OUT_CODES_OFF (33554432UL)            // 32768*1024
#define OUT_LOSS_OFF  (34603008UL)            // + 32768*32
#define TAU 1e-5f
#define INV_N (1.0f/33554432.0f)

typedef __attribute__((ext_vector_type(8))) short s16x8;
typedef __attribute__((ext_vector_type(4))) float f32x4;

__device__ __forceinline__ unsigned short bf16r(float x) {
    unsigned int u = __float_as_uint(x);
    unsigned int r = (u + 0x7FFFu + ((u >> 16) & 1u)) >> 16;
    return (unsigned short)r;
}
__device__ __forceinline__ float bf16f(unsigned short h) {
    return __uint_as_float(((unsigned int)h) << 16);
}
// truncation split: x = hi + lo with hi = trunc-bf16(x), lo = rnd-bf16(x - hi)
__device__ __forceinline__ void split8r(float4 v0, float4 v1, s16x8& h, s16x8& l) {
    float xs[8] = {v0.x, v0.y, v0.z, v0.w, v1.x, v1.y, v1.z, v1.w};
    #pragma unroll
    for (int e = 0; e < 8; ++e) {
        unsigned int u = __float_as_uint(xs[e]);
        unsigned short hh = (unsigned short)(u >> 16);
        h[e] = (short)hh;
        l[e] = (short)bf16r(xs[e] - bf16f(hh));
    }
}

// ============ Kernel A: bf16-split MFMA GEMM1 + MFMA VQ screen =====================
// grid 256 x 512thr (8 waves, 4Mx2N). BM=128, 8 n-tiles of BN=128, BK=32.
// Flattened (nt,kt) loop with register prefetch; stash aliases A/B LDS.
__launch_bounds__(512, 1)
__global__ void k_enc(const float* __restrict__ skills,
                      const float* __restrict__ enc_w,
                      const float* __restrict__ enc_b,
                      const float* __restrict__ cb_g,
                      float* __restrict__ out)
{
    __shared__ __align__(16) char smem[125952];
    typedef unsigned short (*pu40)[40];
    pu40 Ah = (pu40)(smem);                 // [128][40]
    pu40 Al = (pu40)(smem + 10240);
    pu40 Bh = (pu40)(smem + 20480);
    pu40 Bl = (pu40)(smem + 30720);
    pu40 Sh = (pu40)(smem);                 // [512][40] alias over A/B (disjoint in time)
    pu40 Sl = (pu40)(smem + 40960);
    pu40 Ch = (pu40)(smem + 81920);         // [256][40]
    pu40 Cl = (pu40)(smem + 102400);
    float* cnb = (float*)(smem + 122880);   // [256]
    float* Fv  = (float*)(smem + 123904);   // [512]

    const int tid = threadIdx.x;
    const int r0 = blockIdx.x * 128;
    const int wid = tid >> 6, lane = tid & 63;
    const int wm = wid >> 1, wn = wid & 1;
    const int mbase = wm * 32, nbase = wn * 64;
    const int lhi = lane >> 4, llo = lane & 15;
    const int srow = tid >> 2, sq = tid & 3;

    // ---- stage codebook split + cnorm (non-aliased region) ----
    if (tid < 256) {
        const float4* cr = (const float4*)&cb_g[tid * 32];
        float s = 0.f;
        #pragma unroll
        for (int i = 0; i < 8; ++i) {
            float4 v = cr[i];
            float c[4] = {v.x, v.y, v.z, v.w};
            #pragma unroll
            for (int e = 0; e < 4; ++e) {
                unsigned int u = __float_as_uint(c[e]);
                unsigned short hh = (unsigned short)(u >> 16);
                Ch[tid][i*4+e] = hh;
                Cl[tid][i*4+e] = bf16r(c[e] - bf16f(hh));
                s = fmaf(c[e], c[e], s);
            }
        }
        cnb[tid] = s;
    }
    __syncthreads();

    float vq_local = 0.f;
    f32x4 acc[2][4];
    float4 ra0, ra1, rb0, rb1;

    // preload it=0 (nt=0, kt=0)
    {
        const float* ap = &skills[(size_t)(r0 + srow) * 1024 + sq * 8];
        ra0 = *(const float4*)ap; ra1 = *(const float4*)(ap + 4);
        const float* bp = &enc_w[(size_t)srow * 1024 + sq * 8];
        rb0 = *(const float4*)bp; rb1 = *(const float4*)(bp + 4);
    }

    for (int it = 0; it < 256; ++it) {
        const int nt = it >> 5, kt = it & 31;
        const int n0 = nt * 128;
        if (kt == 0) {
            #pragma unroll
            for (int mf = 0; mf < 2; ++mf)
                #pragma unroll
                for (int nf = 0; nf < 4; ++nf) acc[mf][nf] = (f32x4)0.f;
        }
        __syncthreads();                       // prev readers of A/B (or S) done
        {
            s16x8 h, l;
            split8r(ra0, ra1, h, l);
            *(s16x8*)&Ah[srow][sq * 8] = h;
            *(s16x8*)&Al[srow][sq * 8] = l;
            split8r(rb0, rb1, h, l);
            *(s16x8*)&Bh[srow][sq * 8] = h;
            *(s16x8*)&Bl[srow][sq * 8] = l;
        }
        __syncthreads();
        // prefetch it+1 (crosses nt boundary; hidden under MFMA / screen)
        if (it < 255) {
            const int it2 = it + 1, nt2 = it2 >> 5, kt2 = it2 & 31;
            const float* ap = &skills[(size_t)(r0 + srow) * 1024 + kt2 * 32 + sq * 8];
            ra0 = *(const float4*)ap; ra1 = *(const float4*)(ap + 4);
            const float* bp = &enc_w[(size_t)(nt2 * 128 + srow) * 1024 + kt2 * 32 + sq * 8];
            rb0 = *(const float4*)bp; rb1 = *(const float4*)(bp + 4);
        }
        // fragments + 3-pass MFMA
        {
            s16x8 ah[2], al[2], bh[4], bl[4];
            #pragma unroll
            for (int mf = 0; mf < 2; ++mf) {
                const int row = mbase + mf * 16 + llo;
                ah[mf] = *(s16x8*)&Ah[row][lhi * 8];
                al[mf] = *(s16x8*)&Al[row][lhi * 8];
            }
            #pragma unroll
            for (int nf = 0; nf < 4; ++nf) {
                const int row = nbase + nf * 16 + llo;
                bh[nf] = *(s16x8*)&Bh[row][lhi * 8];
                bl[nf] = *(s16x8*)&Bl[row][lhi * 8];
            }
            #pragma unroll
            for (int mf = 0; mf < 2; ++mf)
                #pragma unroll
                for (int nf = 0; nf < 4; ++nf) {
                    acc[mf][nf] = __builtin_amdgcn_mfma_f32_16x16x32_bf16(ah[mf], bh[nf], acc[mf][nf], 0, 0, 0);
                    acc[mf][nf] = __builtin_amdgcn_mfma_f32_16x16x32_bf16(ah[mf], bl[nf], acc[mf][nf], 0, 0, 0);
                    acc[mf][nf] = __builtin_amdgcn_mfma_f32_16x16x32_bf16(al[mf], bh[nf], acc[mf][nf], 0, 0, 0);
                }
        }

        if (kt == 31) {
            __syncthreads();                   // MFMA frag reads done -> stash may clobber A/B
            // ---- bias + stash (bf16 trunc-split) + F partials ----
            float fp[2][4][2];
            #pragma unroll
            for (int mf = 0; mf < 2; ++mf)
                #pragma unroll
                for (int r = 0; r < 4; ++r) { fp[mf][r][0] = 0.f; fp[mf][r][1] = 0.f; }

            #pragma unroll
            for (int mf = 0; mf < 2; ++mf)
                #pragma unroll
                for (int nf = 0; nf < 4; ++nf) {
                    const int n_local = nbase + nf * 16 + llo;
                    const float bias = enc_b[n0 + n_local];
                    const int tl = wn * 2 + (nf >> 1);
                    const int d = ((nf & 1) << 4) + llo;
                    #pragma unroll
                    for (int r = 0; r < 4; ++r) {
                        const int m_local = mbase + mf * 16 + lhi * 4 + r;
                        float val = acc[mf][nf][r] + bias;
                        unsigned int u = __float_as_uint(val);
                        unsigned short hh = (unsigned short)(u >> 16);
                        Sh[m_local * 4 + tl][d] = hh;
                        Sl[m_local * 4 + tl][d] = bf16r(val - bf16f(hh));
                        fp[mf][r][nf >> 1] = fmaf(val, val, fp[mf][r][nf >> 1]);
                    }
                }
            #pragma unroll
            for (int mf = 0; mf < 2; ++mf)
                #pragma unroll
                for (int r = 0; r < 4; ++r)
                    #pragma unroll
                    for (int tt = 0; tt < 2; ++tt) {
                        float f = fp[mf][r][tt];
                        f += __shfl_xor(f, 1); f += __shfl_xor(f, 2);
                        f += __shfl_xor(f, 4); f += __shfl_xor(f, 8);
                        if (llo == 0)
                            Fv[(mbase + mf * 16 + lhi * 4 + r) * 4 + wn * 2 + tt] = f;
                    }
            __syncthreads();

            // ---- MFMA score screen: 4 token-groups of 16 per wave ----
            #pragma unroll
            for (int gi = 0; gi < 4; ++gi) {
                const int g = wid * 4 + gi;
                const int tokrow = g * 16 + llo;
                s16x8 fh = *(s16x8*)&Sh[tokrow][lhi * 8];
                s16x8 fl = *(s16x8*)&Sl[tokrow][lhi * 8];
                float s1[4], s2[4]; int bj[4];
                #pragma unroll
                for (int r = 0; r < 4; ++r) { s1[r] = FLT_MAX; s2[r] = FLT_MAX; bj[r] = 0; }
                for (int jb = 0; jb < 16; ++jb) {
                    const int j = jb * 16 + llo;
                    s16x8 ch = *(s16x8*)&Ch[j][lhi * 8];
                    s16x8 cl = *(s16x8*)&Cl[j][lhi * 8];
                    f32x4 sc = (f32x4)0.f;
                    sc = __builtin_amdgcn_mfma_f32_16x16x32_bf16(fh, ch, sc, 0, 0, 0);
                    sc = __builtin_amdgcn_mfma_f32_16x16x32_bf16(fh, cl, sc, 0, 0, 0);
                    sc = __builtin_amdgcn_mfma_f32_16x16x32_bf16(fl, ch, sc, 0, 0, 0);
                    const float cnv = cnb[j];
                    #pragma unroll
                    for (int r = 0; r < 4; ++r) {
                        float s = fmaf(-2.f, sc[r], cnv);
                        if (s < s1[r])      { s2[r] = s1[r]; s1[r] = s; bj[r] = j; }
                        else if (s < s2[r]) { s2[r] = s; }
                    }
                }
                #pragma unroll
                for (int r = 0; r < 4; ++r) {
                    float a1 = s1[r], a2 = s2[r]; int aj = bj[r];
                    #pragma unroll
                    for (int off = 1; off <= 8; off <<= 1) {
                        float o1 = __shfl_xor(a1, off);
                        float o2 = __shfl_xor(a2, off);
                        int   oj = __shfl_xor(aj, off);
                        if (o1 < a1) { a2 = fminf(a1, o2); a1 = o1; aj = oj; }
                        else         { a2 = fminf(o1, a2); }
                    }
                    if (llo == 0) {
                        const int tok_local = g * 16 + lhi * 4 + r;
                        const float F = Fv[tok_local];
                        float cv = (a2 - a1 < TAU) ? (float)(aj + 512) : (float)aj;
                        const size_t tok = (size_t)(r0 + (tok_local >> 2)) * 32 + nt * 4 + (tok_local & 3);
                        out[OUT_CODES_OFF + tok] = cv;
                        vq_local += F + a1;
                    }
                }
            }
            // loop-top __syncthreads separates screen reads from next staging writes
        }
    }
    // vq loss partial (pre-scaled)
    {
        float v = vq_local;
        #pragma unroll
        for (int off = 32; off >= 1; off >>= 1) v += __shfl_xor(v, off);
        if (lane == 0) atomicAdd(&out[OUT_LOSS_OFF], v * (1.25f * INV_N));
    }
}

// ============ Kernel F: wave-cooperative faithful numpy-f32 fixup (bit-identical) ===
__launch_bounds__(256)
__global__ void k_fix(const float* __restrict__ skills,
                      const float* __restrict__ enc_w,
                      const float* __restrict__ enc_b,
                      const float* __restrict__ cb_g,
                      float* __restrict__ codes)
{
    __shared__ unsigned int cnt;
    __shared__ unsigned short list[256];

    const int tid = threadIdx.x;
    const int base = blockIdx.x * 256;

    if (tid == 0) cnt = 0;
    __syncthreads();
    {
        const int c = (int)codes[base + tid];
        if (c >= 512) {
            unsigned int ix = atomicAdd(&cnt, 1u);
            list[ix] = (unsigned short)tid;
        }
    }
    __syncthreads();
    const unsigned int n = cnt;
    if (n == 0) return;

    const int wv = tid >> 6, lane = tid & 63;
    const int d = lane & 31;

    for (unsigned int i = wv; i < n; i += 4) {
        const int tok = base + (int)list[i];
        const int row = tok >> 5;
        const int t   = tok & 31;

        const float4* s4 = (const float4*)&skills[(size_t)row * 1024];
        const float4* w4 = (const float4*)&enc_w[(size_t)(t * 32 + d) * 1024];
        float v1 = 0.f, v2 = 0.f, v3 = 0.f;
        for (int q = 0; q < 96; ++q) {
            float4 a = s4[q], b = w4[q];
            v1 = fmaf(a.x, b.x, v1); v1 = fmaf(a.y, b.y, v1);
            v1 = fmaf(a.z, b.z, v1); v1 = fmaf(a.w, b.w, v1);
        }
        for (int q = 96; q < 192; ++q) {
            float4 a = s4[q], b = w4[q];
            v2 = fmaf(a.x, b.x, v2); v2 = fmaf(a.y, b.y, v2);
            v2 = fmaf(a.z, b.z, v2); v2 = fmaf(a.w, b.w, v2);
        }
        for (int q = 192; q < 256; ++q) {
            float4 a = s4[q], b = w4[q];
            v3 = fmaf(a.x, b.x, v3); v3 = fmaf(a.y, b.y, v3);
            v3 = fmaf(a.z, b.z, v3); v3 = fmaf(a.w, b.w, v3);
        }
        const float pd = ((v1 + v2) + v3) + enc_b[t * 32 + d];

        float pv[32];
        #pragma unroll
        for (int dd = 0; dd < 32; ++dd) pv[dd] = __shfl(pd, dd);

        float F;
        {
            float s[32];
            #pragma unroll
            for (int dd = 0; dd < 32; ++dd) s[dd] = pv[dd] * pv[dd];
            float r[8];
            #pragma unroll
            for (int j = 0; j < 8; ++j) r[j] = ((s[j] + s[8+j]) + s[16+j]) + s[24+j];
            F = ((r[0] + r[1]) + (r[2] + r[3])) + ((r[4] + r[5]) + (r[6] + r[7]));
        }

        float bs = FLT_MAX; int bj = 0;
        for (int m = 0; m < 4; ++m) {
            const int j = m * 64 + lane;
            const float* cj = &cb_g[j * 32];
            float g = 0.f;
            #pragma unroll
            for (int dd = 0; dd < 32; ++dd) g = fmaf(pv[dd], cj[dd], g);
            float cs[32];
            #pragma unroll
            for (int dd = 0; dd < 32; ++dd) cs[dd] = cj[dd] * cj[dd];
            float r[8];
            #pragma unroll
            for (int jj = 0; jj < 8; ++jj) r[jj] = ((cs[jj] + cs[8+jj]) + cs[16+jj]) + cs[24+jj];
            float cn = ((r[0] + r[1]) + (r[2] + r[3])) + ((r[4] + r[5]) + (r[6] + r[7]));
            float dist = (F - 2.0f * g) + cn;
            if (dist < bs) { bs = dist; bj = j; }
        }
        #pragma unroll
        for (int off = 32; off >= 1; off >>= 1) {
            float os = __shfl_xor(bs, off);
            int   oj = __shfl_xor(bj, off);
            if (os < bs || (os == bs && oj < bj)) { bs = os; bj = oj; }
        }
        if (lane == 0) codes[tok] = (float)bj;
    }
}

// ============ Kernel B: bf16 MFMA GEMM2 (quantized@dec_w^T + b) + recon loss ========
// nb = bid&7 (one dec_w slab per XCD L2), rb = bid>>3; 2-step code/cb/dec_w pipeline.
__launch_bounds__(512)
__global__ void k_dec(const float* __restrict__ skills,
                      const float* __restrict__ cb_g,
                      const float* __restrict__ dec_w,
                      const float* __restrict__ dec_b,
                      const float* __restrict__ codes,
                      float* __restrict__ recon,
                      float* __restrict__ loss_out)
{
    __shared__ unsigned short Qt[128][40], Wt[128][40];

    const int tid = threadIdx.x;
    const int r0 = (blockIdx.x >> 3) * 128;
    const int n0 = (blockIdx.x & 7) * 128;
    const int wid = tid >> 6, lane = tid & 63;
    const int wm = wid >> 1, wn = wid & 1;
    const int mbase = wm * 32, nbase = wn * 64;
    const int lhi = lane >> 4, llo = lane & 15;
    const int srow = tid >> 2, sq = tid & 3;

    f32x4 acc[2][4];
    #pragma unroll
    for (int mf = 0; mf < 2; ++mf)
        #pragma unroll
        for (int nf = 0; nf < 4; ++nf) acc[mf][nf] = (f32x4)0.f;

    // pipeline: cq (cb row for t), rw (dec_w for t), cnext (code for t+1)
    float4 q0, q1, w0, w1;
    int cnext;
    {
        const int c0 = ((int)codes[(size_t)(r0 + srow) * 32 + 0]) & 255;
        const float* cp = &cb_g[c0 * 32 + sq * 8];
        q0 = *(const float4*)cp; q1 = *(const float4*)(cp + 4);
        const float* wp = &dec_w[(size_t)(n0 + srow) * 1024 + sq * 8];
        w0 = *(const float4*)wp; w1 = *(const float4*)(wp + 4);
        cnext = ((int)codes[(size_t)(r0 + srow) * 32 + 1]) & 255;
    }

    for (int t = 0; t < 32; ++t) {
        __syncthreads();
        {
            float xs[8] = {q0.x, q0.y, q0.z, q0.w, q1.x, q1.y, q1.z, q1.w};
            s16x8 h;
            #pragma unroll
            for (int e = 0; e < 8; ++e) h[e] = (short)bf16r(xs[e]);
            *(s16x8*)&Qt[srow][sq * 8] = h;
            float ys[8] = {w0.x, w0.y, w0.z, w0.w, w1.x, w1.y, w1.z, w1.w};
            #pragma unroll
            for (int e = 0; e < 8; ++e) h[e] = (short)bf16r(ys[e]);
            *(s16x8*)&Wt[srow][sq * 8] = h;
        }
        __syncthreads();
        if (t < 31) {
            const float* cp = &cb_g[cnext * 32 + sq * 8];
            q0 = *(const float4*)cp; q1 = *(const float4*)(cp + 4);
            const float* wp = &dec_w[(size_t)(n0 + srow) * 1024 + (t + 1) * 32 + sq * 8];
            w0 = *(const float4*)wp; w1 = *(const float4*)(wp + 4);
            if (t < 30) cnext = ((int)codes[(size_t)(r0 + srow) * 32 + t + 2]) & 255;
        }
        s16x8 aq[2], bw[4];
        #pragma unroll
        for (int mf = 0; mf < 2; ++mf)
            aq[mf] = *(s16x8*)&Qt[mbase + mf * 16 + llo][lhi * 8];
        #pragma unroll
        for (int nf = 0; nf < 4; ++nf)
            bw[nf] = *(s16x8*)&Wt[nbase + nf * 16 + llo][lhi * 8];
        #pragma unroll
        for (int mf = 0; mf < 2; ++mf)
            #pragma unroll
            for (int nf = 0; nf < 4; ++nf)
                acc[mf][nf] = __builtin_amdgcn_mfma_f32_16x16x32_bf16(aq[mf], bw[nf], acc[mf][nf], 0, 0, 0);
    }

    float lsum = 0.f;
    #pragma unroll
    for (int mf = 0; mf < 2; ++mf)
        #pragma unroll
        for (int nf = 0; nf < 4; ++nf) {
            const int col = n0 + nbase + nf * 16 + llo;
            const float bias = dec_b[col];
            #pragma unroll
            for (int r = 0; r < 4; ++r) {
                const int row = r0 + mbase + mf * 16 + lhi * 4 + r;
                float rv = acc[mf][nf][r] + bias;
                float dv = rv - skills[(size_t)row * 1024 + col];
                lsum = fmaf(dv, dv, lsum);
                recon[(size_t)row * 1024 + col] = rv;
            }
        }
    #pragma unroll
    for (int off = 32; off >= 1; off >>= 1) lsum += __shfl_xor(lsum, off);
    if (lane == 0) atomicAdd(loss_out, lsum * INV_N);
}

extern "C" void kernel_launch(void* const* d_in, const int* in_sizes, int n_in,
                              void* d_out, int out_size, void* d_ws, size_t ws_size,
                              hipStream_t stream)
{
    const float* skills = (const float*)d_in[0];
    const float* enc_w  = (const float*)d_in[1];
    const float* enc_b  = (const float*)d_in[2];
    const float* cbg    = (const float*)d_in[3];
    const float* dec_w  = (const float*)d_in[4];
    const float* dec_b  = (const float*)d_in[5];
    float* out = (float*)d_out;

    hipMemsetAsync(out + OUT_LOSS_OFF, 0, 4, stream);
    k_enc<<<dim3(256), dim3(512), 0, stream>>>(skills, enc_w, enc_b, cbg, out);
    k_fix<<<dim3(4096), dim3(256), 0, stream>>>(skills, enc_w, enc_b, cbg, out + OUT_CODES_OFF);
    k_dec<<<dim3(2048), dim3(512), 0, stream>>>(skills, cbg, dec_w, dec_b,
                                                out + OUT_CODES_OFF, out, out + OUT_LOSS_OFF);
}